// Round 1
// baseline (835.634 us; speedup 1.0000x reference)
//
#include <hip/hip_runtime.h>
#include <cfloat>

#define B_DIM 16
#define C_DIM 64
#define N_DIM 2048
#define O_DIM 64
#define K_NN  3
#define TI 128
#define TJ 128

// Lexicographic (d, j) insert into a sorted-ascending top-3. Matches
// jax.lax.top_k tie-break (smaller index first on equal distance).
__device__ __forceinline__ void insert3(double d, int j,
    double &k0, double &k1, double &k2, int &j0, int &j1, int &j2) {
  if ((d < k2) || (d == k2 && j < j2)) {
    if ((d < k1) || (d == k1 && j < j1)) {
      k2 = k1; j2 = j1;
      if ((d < k0) || (d == k0 && j < j0)) {
        k1 = k0; j1 = j0; k0 = d; j0 = j;
      } else { k1 = d; j1 = j; }
    } else { k2 = d; j2 = j; }
  }
}

// ---- kernel 1: per-point squared norms, fp64 (cheap, kills final-add rounding) ----
__global__ __launch_bounds__(256) void norms_kernel(const float* __restrict__ x,
                                                    double* __restrict__ nd) {
  int gid = blockIdx.x * 256 + threadIdx.x;   // [0, B*N)
  int b = gid >> 11;                          // / 2048
  int n = gid & (N_DIM - 1);
  const float* p = x + (size_t)b * C_DIM * N_DIM + n;
  double s = 0.0;
  #pragma unroll
  for (int c = 0; c < C_DIM; ++c) {
    double v = (double)p[(size_t)c * N_DIM];
    s = fma(v, v, s);
  }
  nd[gid] = s;
}

// ---- kernel 1b: transpose W [O][C*K] -> Wt [C*K][O] in workspace ----
__global__ __launch_bounds__(256) void wt_kernel(const float* __restrict__ W,
                                                 float* __restrict__ Wt) {
  int t = blockIdx.x * 256 + threadIdx.x;     // 12288 total
  int o  = t / (C_DIM * K_NN);
  int ck = t - o * (C_DIM * K_NN);
  Wt[ck * O_DIM + o] = W[t];
}

// ---- kernel 2: fused distance GEMM + running top-3 per row ----
// grid = B * (N/TI) = 256 blocks, 256 threads. 8x8 micro-tile per thread.
__global__ __launch_bounds__(256, 1) void topk_kernel(
    const float* __restrict__ x, const double* __restrict__ nd,
    int* __restrict__ topk) {
  __shared__ __align__(16) float At[C_DIM][TI];   // 32 KB
  __shared__ __align__(16) float Bt[C_DIM][TJ];   // 32 KB
  int bid = blockIdx.x;
  int b  = bid >> 4;
  int i0 = (bid & 15) * TI;
  const float* xb = x + (size_t)b * C_DIM * N_DIM;
  const double* ndb = nd + b * N_DIM;
  int t  = threadIdx.x;
  int ty = t >> 4, tx = t & 15;

  // stage A tile once: At[c][i] = x[b][c][i0+i]
  #pragma unroll
  for (int r = 0; r < 8; ++r) {
    int flat = r * 256 + t;
    int c   = flat >> 5;
    int pos = (flat & 31) << 2;
    *(float4*)&At[c][pos] = *(const float4*)(xb + (size_t)c * N_DIM + i0 + pos);
  }

  // per-thread top-3 state for its 8 rows
  double kd[8][3]; int kj[8][3]; float f2[8];
  #pragma unroll
  for (int ii = 0; ii < 8; ++ii) {
    kd[ii][0] = kd[ii][1] = kd[ii][2] = DBL_MAX;
    kj[ii][0] = kj[ii][1] = kj[ii][2] = 0x7fffffff;
    f2[ii] = FLT_MAX;
  }

  for (int jt = 0; jt < N_DIM / TJ; ++jt) {
    int j0 = jt * TJ;
    __syncthreads();   // previous tile's compute done before Bt overwrite
    #pragma unroll
    for (int r = 0; r < 8; ++r) {
      int flat = r * 256 + t;
      int c   = flat >> 5;
      int pos = (flat & 31) << 2;
      *(float4*)&Bt[c][pos] = *(const float4*)(xb + (size_t)c * N_DIM + j0 + pos);
    }
    __syncthreads();

    float acc[8][8];
    #pragma unroll
    for (int ii = 0; ii < 8; ++ii)
      #pragma unroll
      for (int jj = 0; jj < 8; ++jj) acc[ii][jj] = 0.0f;

    // fragment split {g*4, 64+g*4}: 2-way LDS aliasing only (free, m136)
    const float* Ap = &At[0][0] + (ty << 2);
    const float* Bp = &Bt[0][0] + (tx << 2);
    #pragma unroll 4
    for (int c = 0; c < C_DIM; ++c) {
      float a[8], bb[8];
      *(float4*)(&a[0])  = *(const float4*)(Ap + c * TI);
      *(float4*)(&a[4])  = *(const float4*)(Ap + c * TI + 64);
      *(float4*)(&bb[0]) = *(const float4*)(Bp + c * TJ);
      *(float4*)(&bb[4]) = *(const float4*)(Bp + c * TJ + 64);
      #pragma unroll
      for (int ii = 0; ii < 8; ++ii)
        #pragma unroll
        for (int jj = 0; jj < 8; ++jj)
          acc[ii][jj] = fmaf(a[ii], bb[jj], acc[ii][jj]);
    }

    // epilogue: key = n_j - 2*dot (rank-equivalent to dist: n_i is constant per row).
    // float pre-filter (slack 2e-4 > fp32 rounding at |key|<=512), fp64 refine.
    #pragma unroll
    for (int jj = 0; jj < 8; ++jj) {
      int col = (jj < 4) ? ((tx << 2) + jj) : (64 + (tx << 2) + (jj - 4));
      int j = j0 + col;
      double njd = ndb[j];
      float  njf = (float)njd;
      #pragma unroll
      for (int ii = 0; ii < 8; ++ii) {
        float dkf = fmaf(-2.0f, acc[ii][jj], njf);
        if (dkf < f2[ii]) {
          double dk = fma(-2.0, (double)acc[ii][jj], njd);
          insert3(dk, j, kd[ii][0], kd[ii][1], kd[ii][2],
                         kj[ii][0], kj[ii][1], kj[ii][2]);
          f2[ii] = (float)kd[ii][2] + 2e-4f;
        }
      }
    }
  }

  // butterfly merge across the 16 tx-lanes sharing each row (same wave: lanes
  // (ty&3)*16 + tx; xor masks 1,2,4,8 stay inside the 16-group).
  #pragma unroll
  for (int ii = 0; ii < 8; ++ii) {
    #pragma unroll
    for (int m = 1; m < 16; m <<= 1) {
      double t0 = __shfl_xor(kd[ii][0], m, 64);
      double t1 = __shfl_xor(kd[ii][1], m, 64);
      double t2 = __shfl_xor(kd[ii][2], m, 64);
      int    u0 = __shfl_xor(kj[ii][0], m, 64);
      int    u1 = __shfl_xor(kj[ii][1], m, 64);
      int    u2 = __shfl_xor(kj[ii][2], m, 64);
      insert3(t0, u0, kd[ii][0], kd[ii][1], kd[ii][2], kj[ii][0], kj[ii][1], kj[ii][2]);
      insert3(t1, u1, kd[ii][0], kd[ii][1], kd[ii][2], kj[ii][0], kj[ii][1], kj[ii][2]);
      insert3(t2, u2, kd[ii][0], kd[ii][1], kd[ii][2], kj[ii][0], kj[ii][1], kj[ii][2]);
    }
  }
  if (tx == 0) {
    #pragma unroll
    for (int ii = 0; ii < 8; ++ii) {
      int i = i0 + ((ii < 4) ? ((ty << 2) + ii) : (64 + (ty << 2) + (ii - 4)));
      int base = (b * N_DIM + i) * K_NN;
      topk[base + 0] = kj[ii][0];
      topk[base + 1] = kj[ii][1];
      topk[base + 2] = kj[ii][2];
    }
  }
}

// ---- kernel 3: gather neighbors + conv. grid = B*(N/64) = 512 blocks ----
#define NT   64
#define NPAD 68   // pad breaks (ck*stride) % 32 bank aliasing; keeps 16B align
__global__ __launch_bounds__(256) void conv_kernel(
    const float* __restrict__ x, const float* __restrict__ Wt,
    const float* __restrict__ bias, const int* __restrict__ topk,
    float* __restrict__ out) {
  __shared__ __align__(16) float nb[C_DIM * K_NN][NPAD];  // 52224 B -> 3 blocks/CU
  int bid = blockIdx.x;
  int b  = bid >> 5;
  int n0 = (bid & 31) * NT;
  const float* xb = x + (size_t)b * C_DIM * N_DIM;
  const int* tk = topk + (b * N_DIM + n0) * K_NN;
  int t = threadIdx.x;

  // gather stage: nb[c*3+k][n] = x[b][c][ idx[n0+n][k] ]
  for (int f = t; f < C_DIM * K_NN * NT; f += 256) {
    int ck = f >> 6;           // [0,192)
    int n  = f & (NT - 1);
    int c  = ck / K_NN;
    int k  = ck - c * K_NN;
    int j  = tk[n * K_NN + k];
    nb[ck][n] = xb[(size_t)c * N_DIM + j];
  }
  __syncthreads();

  int ng = t & 15, og = t >> 4;    // 4 n's x 4 o's per thread
  float acc[4][4];
  #pragma unroll
  for (int oo = 0; oo < 4; ++oo) {
    float bv = bias[(og << 2) + oo];
    #pragma unroll
    for (int nn = 0; nn < 4; ++nn) acc[oo][nn] = bv;
  }

  const float* nbp = &nb[0][0] + (ng << 2);
  const float* wtp = Wt + (og << 2);
  #pragma unroll 4
  for (int ck = 0; ck < C_DIM * K_NN; ++ck) {
    float4 nv = *(const float4*)(nbp + ck * NPAD);
    float4 wv = *(const float4*)(wtp + ck * O_DIM);   // wave-broadcast, L2-hit
    float na[4] = {nv.x, nv.y, nv.z, nv.w};
    float wa[4] = {wv.x, wv.y, wv.z, wv.w};
    #pragma unroll
    for (int oo = 0; oo < 4; ++oo)
      #pragma unroll
      for (int nn = 0; nn < 4; ++nn)
        acc[oo][nn] = fmaf(wa[oo], na[nn], acc[oo][nn]);
  }

  #pragma unroll
  for (int oo = 0; oo < 4; ++oo) {
    int o = (og << 2) + oo;
    float4 v; v.x = acc[oo][0]; v.y = acc[oo][1]; v.z = acc[oo][2]; v.w = acc[oo][3];
    *(float4*)&out[(size_t)(b * O_DIM + o) * N_DIM + n0 + (ng << 2)] = v;
  }
}

extern "C" void kernel_launch(void* const* d_in, const int* in_sizes, int n_in,
                              void* d_out, int out_size, void* d_ws, size_t ws_size,
                              hipStream_t stream) {
  const float* x    = (const float*)d_in[0];   // [B][C][N]
  const float* W    = (const float*)d_in[1];   // [O][C][K]
  const float* bias = (const float*)d_in[2];   // [O]
  float* out = (float*)d_out;                  // [B][O][N]
  char* ws = (char*)d_ws;
  // ws layout: nd (B*N doubles, 256KB) | topk (B*N*3 ints, 384KB) | Wt (48KB)
  double* nd  = (double*)ws;
  int*    tk  = (int*)(ws + 262144);
  float*  Wt  = (float*)(ws + 262144 + 393216);

  norms_kernel<<<(B_DIM * N_DIM) / 256, 256, 0, stream>>>(x, nd);
  wt_kernel<<<(O_DIM * C_DIM * K_NN) / 256, 256, 0, stream>>>(W, Wt);
  topk_kernel<<<B_DIM * (N_DIM / TI), 256, 0, stream>>>(x, nd, tk);
  conv_kernel<<<B_DIM * (N_DIM / NT), 256, 0, stream>>>(x, Wt, bias, tk, out);
}

// Round 2
// 315.692 us; speedup vs baseline: 2.6470x; 2.6470x over previous
//
#include <hip/hip_runtime.h>
#include <cfloat>

#define B_DIM 16
#define C_DIM 64
#define N_DIM 2048
#define O_DIM 64
#define K_NN  3
#define TI 128
#define TJ 128

// Lexicographic (d, j) insert into sorted-ascending top-3 (fp64, exact path).
// Matches jax.lax.top_k tie-break (smaller index first on equal distance).
__device__ __forceinline__ void insert3d(double d, int j,
    double &k0, double &k1, double &k2, int &j0, int &j1, int &j2) {
  if ((d < k2) || (d == k2 && j < j2)) {
    if ((d < k1) || (d == k1 && j < j1)) {
      k2 = k1; j2 = j1;
      if ((d < k0) || (d == k0 && j < j0)) {
        k1 = k0; j1 = j0; k0 = d; j0 = j;
      } else { k1 = d; j1 = j; }
    } else { k2 = d; j2 = j; }
  }
}

// fp32 candidate insert: sorted-ascending 4-slot. Membership-only (exact
// re-rank happens later), so key-only compare suffices.
__device__ __forceinline__ void insert4f(float d, int j, float* k, int* ji) {
  if (d < k[3]) {
    if (d < k[2]) {
      k[3] = k[2]; ji[3] = ji[2];
      if (d < k[1]) {
        k[2] = k[1]; ji[2] = ji[1];
        if (d < k[0]) { k[1] = k[0]; ji[1] = ji[0]; k[0] = d; ji[0] = j; }
        else { k[1] = d; ji[1] = j; }
      } else { k[2] = d; ji[2] = j; }
    } else { k[3] = d; ji[3] = j; }
  }
}

// ---- kernel 1: per-point squared norms (fp64 exact + fp32 copy) ----
__global__ __launch_bounds__(256) void norms_kernel(const float* __restrict__ x,
                                                    double* __restrict__ nd,
                                                    float* __restrict__ nf) {
  int gid = blockIdx.x * 256 + threadIdx.x;   // [0, B*N)
  int b = gid >> 11;
  int n = gid & (N_DIM - 1);
  const float* p = x + (size_t)b * C_DIM * N_DIM + n;
  double s = 0.0;
  #pragma unroll
  for (int c = 0; c < C_DIM; ++c) {
    double v = (double)p[(size_t)c * N_DIM];
    s = fma(v, v, s);
  }
  nd[gid] = s;
  nf[gid] = (float)s;
}

// ---- kernel 1b: transpose W [O][C*K] -> Wt [C*K][O] ----
__global__ __launch_bounds__(256) void wt_kernel(const float* __restrict__ W,
                                                 float* __restrict__ Wt) {
  int t = blockIdx.x * 256 + threadIdx.x;     // 12288 total
  int o  = t / (C_DIM * K_NN);
  int ck = t - o * (C_DIM * K_NN);
  Wt[ck * O_DIM + o] = W[t];
}

// ---- kernel 2: distance GEMM sweep + fp32 top-4 candidates per (row, jhalf) ----
// grid = B * (N/TI) * 2 = 512 blocks, 256 threads, 8x8 micro-tile.
// All candidate state is fp32/int (~170 VGPR incl. acc) -> no scratch spill.
__global__ __launch_bounds__(256, 2) void topk_kernel(
    const float* __restrict__ x, const float* __restrict__ nf,
    int* __restrict__ cand) {
  __shared__ __align__(16) float At[C_DIM][TI];   // 32 KB
  __shared__ __align__(16) float Bt[C_DIM][TJ];   // 32 KB
  int bid   = blockIdx.x;
  int jhalf = bid & 1;
  int itile = (bid >> 1) & 15;
  int b     = bid >> 5;
  int i0    = itile * TI;
  int jbase = jhalf * (N_DIM / 2);
  const float* xb  = x  + (size_t)b * C_DIM * N_DIM;
  const float* nfb = nf + b * N_DIM;
  int t  = threadIdx.x;
  int ty = t >> 4, tx = t & 15;

  // stage A tile once: At[c][i] = x[b][c][i0+i]
  #pragma unroll
  for (int r = 0; r < 8; ++r) {
    int flat = r * 256 + t;
    int c   = flat >> 5;
    int pos = (flat & 31) << 2;
    *(float4*)&At[c][pos] = *(const float4*)(xb + (size_t)c * N_DIM + i0 + pos);
  }

  // per-thread fp32 top-4 candidates for its 8 rows
  float ck[8][4]; int cj[8][4];
  #pragma unroll
  for (int ii = 0; ii < 8; ++ii) {
    #pragma unroll
    for (int s = 0; s < 4; ++s) { ck[ii][s] = FLT_MAX; cj[ii][s] = 0; }
  }

  for (int jt = 0; jt < (N_DIM / 2) / TJ; ++jt) {
    int j0 = jbase + jt * TJ;
    __syncthreads();   // previous tile's compute done before Bt overwrite
    #pragma unroll
    for (int r = 0; r < 8; ++r) {
      int flat = r * 256 + t;
      int c   = flat >> 5;
      int pos = (flat & 31) << 2;
      *(float4*)&Bt[c][pos] = *(const float4*)(xb + (size_t)c * N_DIM + j0 + pos);
    }
    __syncthreads();

    float acc[8][8];
    #pragma unroll
    for (int ii = 0; ii < 8; ++ii)
      #pragma unroll
      for (int jj = 0; jj < 8; ++jj) acc[ii][jj] = 0.0f;

    // fragment split {g*4, 64+g*4}: 2-way LDS aliasing only (free, m136)
    const float* Ap = &At[0][0] + (ty << 2);
    const float* Bp = &Bt[0][0] + (tx << 2);
    #pragma unroll 4
    for (int c = 0; c < C_DIM; ++c) {
      float a[8], bb[8];
      *(float4*)(&a[0])  = *(const float4*)(Ap + c * TI);
      *(float4*)(&a[4])  = *(const float4*)(Ap + c * TI + 64);
      *(float4*)(&bb[0]) = *(const float4*)(Bp + c * TJ);
      *(float4*)(&bb[4]) = *(const float4*)(Bp + c * TJ + 64);
      #pragma unroll
      for (int ii = 0; ii < 8; ++ii)
        #pragma unroll
        for (int jj = 0; jj < 8; ++jj)
          acc[ii][jj] = fmaf(a[ii], bb[jj], acc[ii][jj]);
    }

    // epilogue: fp32 key = n_j - 2*dot (rank-equivalent; n_i constant per row).
    // fp32 key error ~6e-5 << rank-3 gaps (~1e-3, validated round 1) -> top-4
    // candidate set certainly contains exact top-3 of this half.
    #pragma unroll
    for (int jj = 0; jj < 8; ++jj) {
      int col = (jj < 4) ? ((tx << 2) + jj) : (64 + (tx << 2) + (jj - 4));
      int j = j0 + col;
      float njf = nfb[j];
      #pragma unroll
      for (int ii = 0; ii < 8; ++ii) {
        float keyf = fmaf(-2.0f, acc[ii][jj], njf);
        insert4f(keyf, j, ck[ii], cj[ii]);
      }
    }
  }

  // butterfly merge across the 16 tx-lanes sharing each row (xor masks 1..8
  // stay inside the 16-group; lane = (ty&3)*16 + tx).
  #pragma unroll
  for (int ii = 0; ii < 8; ++ii) {
    #pragma unroll
    for (int m = 1; m < 16; m <<= 1) {
      float tk[4]; int tj[4];
      #pragma unroll
      for (int s = 0; s < 4; ++s) {
        tk[s] = __shfl_xor(ck[ii][s], m, 64);
        tj[s] = __shfl_xor(cj[ii][s], m, 64);
      }
      #pragma unroll
      for (int s = 0; s < 4; ++s) insert4f(tk[s], tj[s], ck[ii], cj[ii]);
    }
  }
  if (tx == 0) {
    #pragma unroll
    for (int ii = 0; ii < 8; ++ii) {
      int i = i0 + ((ii < 4) ? ((ty << 2) + ii) : (64 + (ty << 2) + (ii - 4)));
      int base = ((b * N_DIM + i) * 2 + jhalf) * 4;
      #pragma unroll
      for (int s = 0; s < 4; ++s) cand[base + s] = cj[ii][s];
    }
  }
}

// ---- kernel 2b: exact fp64 re-rank of the 8 candidates per row ----
// fp32*fp32 products are exact in fp64; 64-term fp64 sum error ~1e-13 ->
// selection is effectively exact, same tie-break as reference.
__global__ __launch_bounds__(256) void refine_kernel(
    const float* __restrict__ x, const double* __restrict__ nd,
    const int* __restrict__ cand, int* __restrict__ topk) {
  int gid = blockIdx.x * 256 + threadIdx.x;   // [0, B*N)
  int b = gid >> 11;
  int n = gid & (N_DIM - 1);
  const float* xb = x + (size_t)b * C_DIM * N_DIM;
  const int* cp = cand + gid * 8;

  float xi[C_DIM];
  #pragma unroll
  for (int c = 0; c < C_DIM; ++c) xi[c] = xb[(size_t)c * N_DIM + n];

  double k0 = DBL_MAX, k1 = DBL_MAX, k2 = DBL_MAX;
  int j0 = 0x7fffffff, j1 = 0x7fffffff, j2 = 0x7fffffff;
  for (int s = 0; s < 8; ++s) {
    int j = cp[s];
    double dot = 0.0;
    #pragma unroll
    for (int c = 0; c < C_DIM; ++c)
      dot = fma((double)xi[c], (double)xb[(size_t)c * N_DIM + j], dot);
    double key = fma(-2.0, dot, nd[b * N_DIM + j]);
    insert3d(key, j, k0, k1, k2, j0, j1, j2);
  }
  int base = gid * K_NN;
  topk[base + 0] = j0;
  topk[base + 1] = j1;
  topk[base + 2] = j2;
}

// ---- kernel 3: gather neighbors + conv. grid = B*(N/64) = 512 blocks ----
#define NT   64
#define NPAD 68
__global__ __launch_bounds__(256) void conv_kernel(
    const float* __restrict__ x, const float* __restrict__ Wt,
    const float* __restrict__ bias, const int* __restrict__ topk,
    float* __restrict__ out) {
  __shared__ __align__(16) float nb[C_DIM * K_NN][NPAD];  // 52224 B
  int bid = blockIdx.x;
  int b  = bid >> 5;
  int n0 = (bid & 31) * NT;
  const float* xb = x + (size_t)b * C_DIM * N_DIM;
  const int* tk = topk + (b * N_DIM + n0) * K_NN;
  int t = threadIdx.x;

  for (int f = t; f < C_DIM * K_NN * NT; f += 256) {
    int ckk = f >> 6;
    int n   = f & (NT - 1);
    int c   = ckk / K_NN;
    int k   = ckk - c * K_NN;
    int j   = tk[n * K_NN + k];
    nb[ckk][n] = xb[(size_t)c * N_DIM + j];
  }
  __syncthreads();

  int ng = t & 15, og = t >> 4;
  float acc[4][4];
  #pragma unroll
  for (int oo = 0; oo < 4; ++oo) {
    float bv = bias[(og << 2) + oo];
    #pragma unroll
    for (int nn = 0; nn < 4; ++nn) acc[oo][nn] = bv;
  }

  const float* nbp = &nb[0][0] + (ng << 2);
  const float* wtp = Wt + (og << 2);
  #pragma unroll 4
  for (int ckk = 0; ckk < C_DIM * K_NN; ++ckk) {
    float4 nv = *(const float4*)(nbp + ckk * NPAD);
    float4 wv = *(const float4*)(wtp + ckk * O_DIM);
    float na[4] = {nv.x, nv.y, nv.z, nv.w};
    float wa[4] = {wv.x, wv.y, wv.z, wv.w};
    #pragma unroll
    for (int oo = 0; oo < 4; ++oo)
      #pragma unroll
      for (int nn = 0; nn < 4; ++nn)
        acc[oo][nn] = fmaf(wa[oo], na[nn], acc[oo][nn]);
  }

  #pragma unroll
  for (int oo = 0; oo < 4; ++oo) {
    int o = (og << 2) + oo;
    float4 v; v.x = acc[oo][0]; v.y = acc[oo][1]; v.z = acc[oo][2]; v.w = acc[oo][3];
    *(float4*)&out[(size_t)(b * O_DIM + o) * N_DIM + n0 + (ng << 2)] = v;
  }
}

extern "C" void kernel_launch(void* const* d_in, const int* in_sizes, int n_in,
                              void* d_out, int out_size, void* d_ws, size_t ws_size,
                              hipStream_t stream) {
  const float* x    = (const float*)d_in[0];   // [B][C][N]
  const float* W    = (const float*)d_in[1];   // [O][C][K]
  const float* bias = (const float*)d_in[2];   // [O]
  float* out = (float*)d_out;                  // [B][O][N]
  char* ws = (char*)d_ws;
  // ws layout (bytes):
  //   nd   double[B*N]        @ 0        (256 KB)
  //   nf   float [B*N]        @ 262144   (128 KB)
  //   cand int   [B*N][2][4]  @ 393216   (1 MB)
  //   topk int   [B*N][3]     @ 1441792  (384 KB)
  //   Wt   float [C*K][O]     @ 1835008  (48 KB)
  double* nd  = (double*)ws;
  float*  nf  = (float*)(ws + 262144);
  int*    cd  = (int*)(ws + 393216);
  int*    tk  = (int*)(ws + 1441792);
  float*  Wt  = (float*)(ws + 1835008);

  norms_kernel<<<(B_DIM * N_DIM) / 256, 256, 0, stream>>>(x, nd, nf);
  wt_kernel<<<(O_DIM * C_DIM * K_NN) / 256, 256, 0, stream>>>(W, Wt);
  topk_kernel<<<B_DIM * (N_DIM / TI) * 2, 256, 0, stream>>>(x, nf, cd);
  refine_kernel<<<(B_DIM * N_DIM) / 256, 256, 0, stream>>>(x, nd, cd, tk);
  conv_kernel<<<B_DIM * (N_DIM / NT), 256, 0, stream>>>(x, Wt, bias, tk, out);
}

// Round 4
// 246.954 us; speedup vs baseline: 3.3838x; 1.2783x over previous
//
#include <hip/hip_runtime.h>
#include <cfloat>
#include <climits>

#define B_DIM 16
#define C_DIM 64
#define N_DIM 2048
#define O_DIM 64
#define K_NN  3

typedef __attribute__((ext_vector_type(8))) short bf16x8;
typedef __attribute__((ext_vector_type(4))) float floatx4;

__device__ __forceinline__ unsigned short f32_to_bf16_rne(float f) {
  unsigned int u = __float_as_uint(f);
  return (unsigned short)((u + 0x7fffu + ((u >> 16) & 1u)) >> 16);
}
__device__ __forceinline__ float bf16_to_f32(unsigned short h) {
  return __uint_as_float(((unsigned int)h) << 16);
}

// Lexicographic (d, j) insert into sorted-ascending top-3 (fp64, exact path).
__device__ __forceinline__ void insert3d(double d, int j,
    double &k0, double &k1, double &k2, int &j0, int &j1, int &j2) {
  if ((d < k2) || (d == k2 && j < j2)) {
    if ((d < k1) || (d == k1 && j < j1)) {
      k2 = k1; j2 = j1;
      if ((d < k0) || (d == k0 && j < j0)) {
        k1 = k0; j1 = j0; k0 = d; j0 = j;
      } else { k1 = d; j1 = j; }
    } else { k2 = d; j2 = j; }
  }
}

// fp32 candidate insert (membership only; exact re-rank later).
__device__ __forceinline__ void insert4f(float d, int j, float* k, int* ji) {
  if (d < k[3]) {
    if (d < k[2]) {
      k[3] = k[2]; ji[3] = ji[2];
      if (d < k[1]) {
        k[2] = k[1]; ji[2] = ji[1];
        if (d < k[0]) { k[1] = k[0]; ji[1] = ji[0]; k[0] = d; ji[0] = j; }
        else { k[1] = d; ji[1] = j; }
      } else { k[2] = d; ji[2] = j; }
    } else { k[3] = d; ji[3] = j; }
  }
}

// ---- kernel 1: transpose x -> xT [B][N][C] (fp32) + fp64/fp32 norms ----
__global__ __launch_bounds__(256) void prep_kernel(
    const float* __restrict__ x, float* __restrict__ xT,
    double* __restrict__ nd, float* __restrict__ nf) {
  __shared__ __align__(16) float xs[C_DIM][68];
  int bid = blockIdx.x;              // B * N/64 = 512
  int b  = bid >> 5;
  int n0 = (bid & 31) * 64;
  int t = threadIdx.x;
  const float* xb = x + (size_t)b * C_DIM * N_DIM;
  #pragma unroll
  for (int r = 0; r < 4; ++r) {
    int idx = r * 256 + t;           // 1024 float4 tasks
    int c = idx >> 4;
    int q = idx & 15;
    *(float4*)&xs[c][q * 4] = *(const float4*)(xb + (size_t)c * N_DIM + n0 + q * 4);
  }
  __syncthreads();
  int n = t >> 2, cg = t & 3;        // 64 n x 4 c-groups of 16
  float v[16];
  #pragma unroll
  for (int cc = 0; cc < 16; ++cc) v[cc] = xs[cg * 16 + cc][n];
  double ps = 0.0;
  #pragma unroll
  for (int cc = 0; cc < 16; ++cc) ps = fma((double)v[cc], (double)v[cc], ps);
  ps += __shfl_xor(ps, 1, 64);
  ps += __shfl_xor(ps, 2, 64);       // lanes t^1,t^2 share n (cg bits)
  size_t rowbase = ((size_t)b * N_DIM + n0 + n) * C_DIM + cg * 16;
  #pragma unroll
  for (int q = 0; q < 4; ++q) {
    float4 w; w.x = v[q*4]; w.y = v[q*4+1]; w.z = v[q*4+2]; w.w = v[q*4+3];
    *(float4*)&xT[rowbase + q * 4] = w;
  }
  if (cg == 0) {
    nd[b * N_DIM + n0 + n] = ps;
    nf[b * N_DIM + n0 + n] = (float)ps;
  }
}

// ---- kernel 1b: transpose W [O][C*K] -> Wt [C*K][O] ----
__global__ __launch_bounds__(256) void wt_kernel(const float* __restrict__ W,
                                                 float* __restrict__ Wt) {
  int t = blockIdx.x * 256 + threadIdx.x;
  int o  = t / (C_DIM * K_NN);
  int ck = t - o * (C_DIM * K_NN);
  Wt[ck * O_DIM + o] = W[t];
}

// ---- kernel 2: split-bf16 MFMA distance sweep + fp32 top-4 candidates ----
// grid = B*16*2 = 512 blocks, 256 thr (4 waves). Block: 128 i x 1024 j-half.
// LDS = 4 x 16KB = 64KB exactly (static limit). Bank conflicts handled by
// XOR chunk swizzle: 16B chunk q of row r lives at chunk q^(r&7). Staging
// writes tile 1KB/wave linearly (conflict-free); frag reads have
// row&7 == col&7 -> 8 bank-groups covered, <=2-way aliasing (free, m136).
#define SWIZ(row, chunk) ((((chunk) ^ ((row) & 7)) << 3))
__global__ __launch_bounds__(256, 2) void topk_kernel(
    const float* __restrict__ xT, const float* __restrict__ nf,
    int* __restrict__ cand) {
  __shared__ __align__(16) unsigned short Ah[128][64], Al[128][64],
                                          Bh[128][64], Bl[128][64];
  int bid   = blockIdx.x;
  int jhalf = bid & 1;
  int itile = (bid >> 1) & 15;
  int b     = bid >> 5;
  int i0    = itile * 128;
  int jbase = jhalf * (N_DIM / 2);
  int t = threadIdx.x;
  int w = t >> 6, lane = t & 63, quad = lane >> 4, col = lane & 15;
  const float* xTb = xT + (size_t)b * N_DIM * C_DIM;
  const float* nfb = nf + b * N_DIM;

  // stage A tile (rows i0..i0+127), split hi/lo on the fly
  #pragma unroll
  for (int p = 0; p < 4; ++p) {
    int u = p * 256 + t;             // 1024 tasks: 128 rows x 8 chunks
    int cg = u & 7;
    int row = u >> 3;
    const float* src = xTb + (size_t)(i0 + row) * C_DIM + cg * 8;
    float4 v0 = *(const float4*)src;
    float4 v1 = *(const float4*)(src + 4);
    float vv[8] = {v0.x, v0.y, v0.z, v0.w, v1.x, v1.y, v1.z, v1.w};
    unsigned int hp[4], lp[4];
    #pragma unroll
    for (int e = 0; e < 4; ++e) {
      unsigned short h0 = f32_to_bf16_rne(vv[2*e]);
      unsigned short h1 = f32_to_bf16_rne(vv[2*e+1]);
      unsigned short l0 = f32_to_bf16_rne(vv[2*e]   - bf16_to_f32(h0));
      unsigned short l1 = f32_to_bf16_rne(vv[2*e+1] - bf16_to_f32(h1));
      hp[e] = (unsigned)h0 | ((unsigned)h1 << 16);
      lp[e] = (unsigned)l0 | ((unsigned)l1 << 16);
    }
    *(uint4*)&Ah[row][SWIZ(row, cg)] = *(uint4*)hp;
    *(uint4*)&Al[row][SWIZ(row, cg)] = *(uint4*)lp;
  }

  float ck[8][4]; int cj[8][4];
  #pragma unroll
  for (int ii = 0; ii < 8; ++ii)
    #pragma unroll
    for (int s = 0; s < 4; ++s) { ck[ii][s] = FLT_MAX; cj[ii][s] = 0; }

  int arow0 = w * 32 + col, arow1 = arow0 + 16;
  int csw = col & 7;                 // row&7 == col&7 for all frag rows

  for (int js = 0; js < 8; ++js) {
    int j0 = jbase + js * 128;
    __syncthreads();                 // prior compute done before B overwrite
    #pragma unroll
    for (int p = 0; p < 4; ++p) {
      int u = p * 256 + t;
      int cg = u & 7;
      int row = u >> 3;
      const float* src = xTb + (size_t)(j0 + row) * C_DIM + cg * 8;
      float4 v0 = *(const float4*)src;
      float4 v1 = *(const float4*)(src + 4);
      float vv[8] = {v0.x, v0.y, v0.z, v0.w, v1.x, v1.y, v1.z, v1.w};
      unsigned int hp[4], lp[4];
      #pragma unroll
      for (int e = 0; e < 4; ++e) {
        unsigned short h0 = f32_to_bf16_rne(vv[2*e]);
        unsigned short h1 = f32_to_bf16_rne(vv[2*e+1]);
        unsigned short l0 = f32_to_bf16_rne(vv[2*e]   - bf16_to_f32(h0));
        unsigned short l1 = f32_to_bf16_rne(vv[2*e+1] - bf16_to_f32(h1));
        hp[e] = (unsigned)h0 | ((unsigned)h1 << 16);
        lp[e] = (unsigned)l0 | ((unsigned)l1 << 16);
      }
      *(uint4*)&Bh[row][SWIZ(row, cg)] = *(uint4*)hp;
      *(uint4*)&Bl[row][SWIZ(row, cg)] = *(uint4*)lp;
    }
    __syncthreads();

    floatx4 acc[2][8];
    #pragma unroll
    for (int it = 0; it < 2; ++it)
      #pragma unroll
      for (int jt = 0; jt < 8; ++jt)
        acc[it][jt] = (floatx4){0.f, 0.f, 0.f, 0.f};

    #pragma unroll
    for (int ks = 0; ks < 2; ++ks) {
      int ph = ((ks * 4 + quad) ^ csw) << 3;   // swizzled element offset
      bf16x8 ah0 = *(const bf16x8*)&Ah[arow0][ph];
      bf16x8 al0 = *(const bf16x8*)&Al[arow0][ph];
      bf16x8 ah1 = *(const bf16x8*)&Ah[arow1][ph];
      bf16x8 al1 = *(const bf16x8*)&Al[arow1][ph];
      #pragma unroll
      for (int jt = 0; jt < 8; ++jt) {
        bf16x8 bh = *(const bf16x8*)&Bh[jt * 16 + col][ph];
        bf16x8 bl = *(const bf16x8*)&Bl[jt * 16 + col][ph];
        acc[0][jt] = __builtin_amdgcn_mfma_f32_16x16x32_bf16(al0, bh, acc[0][jt], 0, 0, 0);
        acc[0][jt] = __builtin_amdgcn_mfma_f32_16x16x32_bf16(ah0, bl, acc[0][jt], 0, 0, 0);
        acc[0][jt] = __builtin_amdgcn_mfma_f32_16x16x32_bf16(ah0, bh, acc[0][jt], 0, 0, 0);
        acc[1][jt] = __builtin_amdgcn_mfma_f32_16x16x32_bf16(al1, bh, acc[1][jt], 0, 0, 0);
        acc[1][jt] = __builtin_amdgcn_mfma_f32_16x16x32_bf16(ah1, bl, acc[1][jt], 0, 0, 0);
        acc[1][jt] = __builtin_amdgcn_mfma_f32_16x16x32_bf16(ah1, bh, acc[1][jt], 0, 0, 0);
      }
    }

    // epilogue: key = n_j - 2*dot (rank-equiv; n_i const per row).
    // C/D layout: col = lane&15 (j=n), row = quad*4 + reg (i=m) [m89]
    #pragma unroll
    for (int jt = 0; jt < 8; ++jt) {
      int j = j0 + jt * 16 + col;
      float njf = nfb[j];
      #pragma unroll
      for (int it = 0; it < 2; ++it)
        #pragma unroll
        for (int r = 0; r < 4; ++r) {
          float key = fmaf(-2.0f, acc[it][jt][r], njf);
          insert4f(key, j, ck[it * 4 + r], cj[it * 4 + r]);
        }
    }
  }

  // merge across the 16 col-lanes (same quad -> same i-rows)
  #pragma unroll
  for (int ii = 0; ii < 8; ++ii) {
    #pragma unroll
    for (int m = 1; m < 16; m <<= 1) {
      float tk[4]; int tj[4];
      #pragma unroll
      for (int s = 0; s < 4; ++s) {
        tk[s] = __shfl_xor(ck[ii][s], m, 64);
        tj[s] = __shfl_xor(cj[ii][s], m, 64);
      }
      #pragma unroll
      for (int s = 0; s < 4; ++s) insert4f(tk[s], tj[s], ck[ii], cj[ii]);
    }
  }
  if (col == 0) {
    #pragma unroll
    for (int ii = 0; ii < 8; ++ii) {
      int it = ii >> 2, r = ii & 3;
      int i = i0 + w * 32 + it * 16 + quad * 4 + r;
      int base = ((b * N_DIM + i) * 2 + jhalf) * 4;
      #pragma unroll
      for (int s = 0; s < 4; ++s) cand[base + s] = cj[ii][s];
    }
  }
}

// ---- kernel 2b: exact fp64 re-rank, wave-per-row (lane = channel) ----
// grid = (B*N)/4 = 8192 blocks (4 waves/block, 1 row per wave).
__global__ __launch_bounds__(256) void refine_kernel(
    const float* __restrict__ xT, const double* __restrict__ nd,
    const int* __restrict__ cand, int* __restrict__ topk) {
  int lane = threadIdx.x & 63;
  int row = blockIdx.x * 4 + (threadIdx.x >> 6);   // [0, B*N)
  int b = row >> 11;
  int n = row & (N_DIM - 1);
  const float* xtb = xT + (size_t)b * N_DIM * C_DIM;
  double xi = (double)xtb[(size_t)n * C_DIM + lane];
  const int* cp = cand + row * 8;
  double k0 = DBL_MAX, k1 = DBL_MAX, k2 = DBL_MAX;
  int j0 = INT_MAX, j1 = INT_MAX, j2 = INT_MAX;
  #pragma unroll
  for (int s = 0; s < 8; ++s) {
    int j = cp[s];
    double p = xi * (double)xtb[(size_t)j * C_DIM + lane];
    #pragma unroll
    for (int m = 1; m < 64; m <<= 1) p += __shfl_xor(p, m, 64);
    double key = fma(-2.0, p, nd[b * N_DIM + j]);
    insert3d(key, j, k0, k1, k2, j0, j1, j2);
  }
  if (lane == 0) {
    int base = row * K_NN;
    topk[base + 0] = j0;
    topk[base + 1] = j1;
    topk[base + 2] = j2;
  }
}

// ---- kernel 3: gather neighbors (coalesced via xT) + conv ----
#define NT   64
#define NPAD 68
__global__ __launch_bounds__(256) void conv_kernel(
    const float* __restrict__ xT, const float* __restrict__ Wt,
    const float* __restrict__ bias, const int* __restrict__ topk,
    float* __restrict__ out) {
  __shared__ __align__(16) float nb[C_DIM * K_NN][NPAD];  // 52224 B
  int bid = blockIdx.x;
  int b  = bid >> 5;
  int n0 = (bid & 31) * NT;
  const float* xtb = xT + (size_t)b * N_DIM * C_DIM;
  const int* tk = topk + (b * N_DIM + n0) * K_NN;
  int t = threadIdx.x;

  #pragma unroll
  for (int p = 0; p < 12; ++p) {
    int u = p * 256 + t;            // 3072 tasks: 192 rows x 16 segs
    int seg = u & 15;
    int r   = u >> 4;               // r = k*64 + n
    int k = r >> 6, n = r & 63;
    int j = tk[n * K_NN + k];
    float4 v = *(const float4*)(xtb + (size_t)j * C_DIM + seg * 4);
    nb[(seg * 4 + 0) * 3 + k][n] = v.x;
    nb[(seg * 4 + 1) * 3 + k][n] = v.y;
    nb[(seg * 4 + 2) * 3 + k][n] = v.z;
    nb[(seg * 4 + 3) * 3 + k][n] = v.w;
  }
  __syncthreads();

  int ng = t & 15, og = t >> 4;
  float acc[4][4];
  #pragma unroll
  for (int oo = 0; oo < 4; ++oo) {
    float bv = bias[(og << 2) + oo];
    #pragma unroll
    for (int nn = 0; nn < 4; ++nn) acc[oo][nn] = bv;
  }
  const float* nbp = &nb[0][0] + (ng << 2);
  const float* wtp = Wt + (og << 2);
  #pragma unroll 4
  for (int ckk = 0; ckk < C_DIM * K_NN; ++ckk) {
    float4 nv = *(const float4*)(nbp + ckk * NPAD);
    float4 wv = *(const float4*)(wtp + ckk * O_DIM);
    float na[4] = {nv.x, nv.y, nv.z, nv.w};
    float wa[4] = {wv.x, wv.y, wv.z, wv.w};
    #pragma unroll
    for (int oo = 0; oo < 4; ++oo)
      #pragma unroll
      for (int nn = 0; nn < 4; ++nn)
        acc[oo][nn] = fmaf(wa[oo], na[nn], acc[oo][nn]);
  }
  #pragma unroll
  for (int oo = 0; oo < 4; ++oo) {
    int o = (og << 2) + oo;
    float4 v; v.x = acc[oo][0]; v.y = acc[oo][1]; v.z = acc[oo][2]; v.w = acc[oo][3];
    *(float4*)&out[(size_t)(b * O_DIM + o) * N_DIM + n0 + (ng << 2)] = v;
  }
}

extern "C" void kernel_launch(void* const* d_in, const int* in_sizes, int n_in,
                              void* d_out, int out_size, void* d_ws, size_t ws_size,
                              hipStream_t stream) {
  const float* x    = (const float*)d_in[0];   // [B][C][N]
  const float* W    = (const float*)d_in[1];   // [O][C][K]
  const float* bias = (const float*)d_in[2];   // [O]
  float* out = (float*)d_out;                  // [B][O][N]
  char* ws = (char*)d_ws;
  // ws layout (bytes):
  //   xT   float [B][N][C]    @ 0         (8 MB)
  //   nd   double[B*N]        @ 8388608   (256 KB)
  //   nf   float [B*N]        @ 8650752   (128 KB)
  //   cand int   [B*N][2][4]  @ 8781824   (1 MB)
  //   topk int   [B*N][3]     @ 9830400   (384 KB)
  //   Wt   float [C*K][O]     @ 10223616  (48 KB)
  float*  xT = (float*)ws;
  double* nd = (double*)(ws + 8388608);
  float*  nf = (float*)(ws + 8650752);
  int*    cd = (int*)(ws + 8781824);
  int*    tk = (int*)(ws + 9830400);
  float*  Wt = (float*)(ws + 10223616);

  prep_kernel<<<B_DIM * (N_DIM / 64), 256, 0, stream>>>(x, xT, nd, nf);
  wt_kernel<<<(O_DIM * C_DIM * K_NN) / 256, 256, 0, stream>>>(W, Wt);
  topk_kernel<<<B_DIM * 16 * 2, 256, 0, stream>>>(xT, nf, cd);
  refine_kernel<<<(B_DIM * N_DIM) / 4, 256, 0, stream>>>(xT, nd, cd, tk);
  conv_kernel<<<B_DIM * (N_DIM / NT), 256, 0, stream>>>(xT, Wt, bias, tk, out);
}

// Round 6
// 179.590 us; speedup vs baseline: 4.6530x; 1.3751x over previous
//
#include <hip/hip_runtime.h>
#include <cfloat>
#include <climits>

#define B_DIM 16
#define C_DIM 64
#define N_DIM 2048
#define O_DIM 64
#define K_NN  3

typedef __attribute__((ext_vector_type(8))) short bf16x8;
typedef __attribute__((ext_vector_type(4))) float floatx4;

__device__ __forceinline__ unsigned short f32_to_bf16_rne(float f) {
  unsigned int u = __float_as_uint(f);
  return (unsigned short)((u + 0x7fffu + ((u >> 16) & 1u)) >> 16);
}
__device__ __forceinline__ float bf16_to_f32(unsigned short h) {
  return __uint_as_float(((unsigned int)h) << 16);
}

// Lexicographic (d, j) insert into sorted-ascending top-3 (fp64, exact path).
// Branchless; assignment order reads lower slots before they are modified.
__device__ __forceinline__ void insert3d(double d, int j,
    double &k0, double &k1, double &k2, int &j0, int &j1, int &j2) {
  bool c2 = (d < k2) || (d == k2 && j < j2);
  bool c1 = (d < k1) || (d == k1 && j < j1);
  bool c0 = (d < k0) || (d == k0 && j < j0);
  k2 = c1 ? k1 : (c2 ? d : k2);
  j2 = c1 ? j1 : (c2 ? j : j2);
  k1 = c0 ? k0 : (c1 ? d : k1);
  j1 = c0 ? j0 : (c1 ? j : j1);
  k0 = c0 ? d : k0;
  j0 = c0 ? j : j0;
}

// Branchless fp32 top-4 insert (membership only; exact re-rank later).
__device__ __forceinline__ void ins4(float key, int jv, float* k, int* j) {
  bool c3 = key < k[3], c2 = key < k[2], c1 = key < k[1], c0 = key < k[0];
  k[3] = c2 ? k[2] : (c3 ? key : k[3]);
  j[3] = c2 ? j[2] : (c3 ? jv  : j[3]);
  k[2] = c1 ? k[1] : (c2 ? key : k[2]);
  j[2] = c1 ? j[1] : (c2 ? jv  : j[2]);
  k[1] = c0 ? k[0] : (c1 ? key : k[1]);
  j[1] = c0 ? j[0] : (c1 ? jv  : j[1]);
  k[0] = c0 ? key : k[0];
  j[0] = c0 ? jv  : j[0];
}

// ---- kernel 1: x -> xT fp32 [B][N][C], bf16 hi/lo split (chunk-swizzled
// in memory: 16B chunk q of row n stored at q^(n&7)), fp64+fp32 norms ----
__global__ __launch_bounds__(256) void prep_kernel(
    const float* __restrict__ x, float* __restrict__ xT,
    unsigned short* __restrict__ xTh, unsigned short* __restrict__ xTl,
    double* __restrict__ nd, float* __restrict__ nf) {
  __shared__ __align__(16) float xs[C_DIM][68];
  int bid = blockIdx.x;              // B * N/64 = 512
  int b  = bid >> 5;
  int n0 = (bid & 31) * 64;
  int t = threadIdx.x;
  const float* xb = x + (size_t)b * C_DIM * N_DIM;
  #pragma unroll
  for (int r = 0; r < 4; ++r) {
    int idx = r * 256 + t;           // 1024 float4 tasks
    int c = idx >> 4;
    int qq = idx & 15;
    *(float4*)&xs[c][qq * 4] = *(const float4*)(xb + (size_t)c * N_DIM + n0 + qq * 4);
  }
  __syncthreads();
  int n = t >> 2, cg = t & 3;        // 64 n x 4 c-groups of 16
  float v[16];
  #pragma unroll
  for (int cc = 0; cc < 16; ++cc) v[cc] = xs[cg * 16 + cc][n];
  double ps = 0.0;
  #pragma unroll
  for (int cc = 0; cc < 16; ++cc) ps = fma((double)v[cc], (double)v[cc], ps);
  ps += __shfl_xor(ps, 1, 64);
  ps += __shfl_xor(ps, 2, 64);       // lanes t^1,t^2 share n
  size_t row = (size_t)b * N_DIM + n0 + n;
  // R5 bug was here: the cg*16 channel offset was dropped -> channels 16..63
  // of every xT row stayed 0xAA-poisoned. Restored.
  #pragma unroll
  for (int qq = 0; qq < 4; ++qq) {
    float4 wv; wv.x = v[qq*4]; wv.y = v[qq*4+1]; wv.z = v[qq*4+2]; wv.w = v[qq*4+3];
    *(float4*)&xT[row * C_DIM + cg * 16 + qq * 4] = wv;
  }
  // bf16 hi/lo split, two 8-element chunks per thread, swizzled store
  unsigned short hh[16], ll[16];
  #pragma unroll
  for (int cc = 0; cc < 16; ++cc) {
    hh[cc] = f32_to_bf16_rne(v[cc]);
    ll[cc] = f32_to_bf16_rne(v[cc] - bf16_to_f32(hh[cc]));
  }
  #pragma unroll
  for (int e = 0; e < 2; ++e) {
    int phys = (2 * cg + e) ^ (n & 7);
    unsigned int hp[4], lp[4];
    #pragma unroll
    for (int xk = 0; xk < 4; ++xk) {
      hp[xk] = (unsigned)hh[e*8 + 2*xk] | ((unsigned)hh[e*8 + 2*xk + 1] << 16);
      lp[xk] = (unsigned)ll[e*8 + 2*xk] | ((unsigned)ll[e*8 + 2*xk + 1] << 16);
    }
    ((uint4*)xTh)[row * 8 + phys] = *(uint4*)hp;
    ((uint4*)xTl)[row * 8 + phys] = *(uint4*)lp;
  }
  if (cg == 0) {
    nd[row] = ps;
    nf[row] = (float)ps;
  }
}

// ---- kernel 1b: transpose W [O][C*K] -> Wt [C*K][O] ----
__global__ __launch_bounds__(256) void wt_kernel(const float* __restrict__ W,
                                                 float* __restrict__ Wt) {
  int t = blockIdx.x * 256 + threadIdx.x;
  int o  = t / (C_DIM * K_NN);
  int ck = t - o * (C_DIM * K_NN);
  Wt[ck * O_DIM + o] = W[t];
}

// ---- kernel 2: split-bf16 MFMA distance sweep, swapped operands ----
// grid = B*16*4 = 1024 blocks (itile x j-quarter), 256 thr (4 waves).
// A-operand = J-tile (LDS, 32KB total), B-operand = I-frags (registers).
// acc[it][jt]: rows m = j (quad*4+reg), cols n = i (lane&15) -> per lane
// only 2 candidate rows (16 VGPRs of top-4 state).
__global__ __launch_bounds__(256, 3) void topk_kernel(
    const unsigned short* __restrict__ xTh, const unsigned short* __restrict__ xTl,
    const float* __restrict__ nf, int* __restrict__ cand) {
  __shared__ __align__(16) unsigned short Jh[128 * 64];  // 16 KB
  __shared__ __align__(16) unsigned short Jl[128 * 64];  // 16 KB
  int bid   = blockIdx.x;
  int q     = bid & 3;               // j-quarter
  int itile = (bid >> 2) & 15;
  int b     = bid >> 6;
  int i0    = itile * 128;
  int jq0   = q * 512;
  int t = threadIdx.x;
  int w = t >> 6, lane = t & 63, quad = lane >> 4, col = lane & 15;
  int csw = col & 7;
  const unsigned short* xh = xTh + (size_t)b * N_DIM * 64;
  const unsigned short* xl = xTl + (size_t)b * N_DIM * 64;
  const float* nfb = nf + b * N_DIM;

  // I-frags (B operand) once from global. row&7 == col&7 == csw.
  bf16x8 ih[2][2], il[2][2];         // [it][ks]
  #pragma unroll
  for (int it = 0; it < 2; ++it)
    #pragma unroll
    for (int ks = 0; ks < 2; ++ks) {
      size_t row = i0 + w * 32 + it * 16 + col;
      int phys = (ks * 4 + quad) ^ csw;
      ih[it][ks] = *(const bf16x8*)(xh + row * 64 + phys * 8);
      il[it][ks] = *(const bf16x8*)(xl + row * 64 + phys * 8);
    }

  float ck[2][4]; int cj[2][4];
  #pragma unroll
  for (int it = 0; it < 2; ++it)
    #pragma unroll
    for (int s = 0; s < 4; ++s) { ck[it][s] = FLT_MAX; cj[it][s] = 0; }

  int a0 = col * 64 + ((quad ^ csw) * 8);        // ks=0 frag offset (shorts)
  int a1 = col * 64 + (((4 + quad) ^ csw) * 8);  // ks=1

  for (int js = 0; js < 4; ++js) {
    int j0 = jq0 + js * 128;
    __syncthreads();                 // prior frag reads done before overwrite
    {
      // stage 32 rows (Jh+Jl) per wave: pure 16B copies, layout verbatim
      const unsigned short* sh = xh + (size_t)(j0 + w * 32) * 64;
      const unsigned short* sl = xl + (size_t)(j0 + w * 32) * 64;
      unsigned short* dh = &Jh[w * 32 * 64];
      unsigned short* dl = &Jl[w * 32 * 64];
      int off = lane * 8;
      #pragma unroll
      for (int k2 = 0; k2 < 4; ++k2) {
        *(uint4*)(dh + k2 * 512 + off) = *(const uint4*)(sh + k2 * 512 + off);
        *(uint4*)(dl + k2 * 512 + off) = *(const uint4*)(sl + k2 * 512 + off);
      }
    }
    __syncthreads();

    floatx4 acc[2][8];
    #pragma unroll
    for (int it = 0; it < 2; ++it)
      #pragma unroll
      for (int jt = 0; jt < 8; ++jt)
        acc[it][jt] = (floatx4){0.f, 0.f, 0.f, 0.f};

    #pragma unroll
    for (int ks = 0; ks < 2; ++ks) {
      int ab = ks ? a1 : a0;
      #pragma unroll
      for (int jt = 0; jt < 8; ++jt) {
        bf16x8 jh = *(const bf16x8*)&Jh[jt * 1024 + ab];
        bf16x8 jl = *(const bf16x8*)&Jl[jt * 1024 + ab];
        acc[0][jt] = __builtin_amdgcn_mfma_f32_16x16x32_bf16(jl, ih[0][ks], acc[0][jt], 0, 0, 0);
        acc[0][jt] = __builtin_amdgcn_mfma_f32_16x16x32_bf16(jh, il[0][ks], acc[0][jt], 0, 0, 0);
        acc[0][jt] = __builtin_amdgcn_mfma_f32_16x16x32_bf16(jh, ih[0][ks], acc[0][jt], 0, 0, 0);
        acc[1][jt] = __builtin_amdgcn_mfma_f32_16x16x32_bf16(jl, ih[1][ks], acc[1][jt], 0, 0, 0);
        acc[1][jt] = __builtin_amdgcn_mfma_f32_16x16x32_bf16(jh, il[1][ks], acc[1][jt], 0, 0, 0);
        acc[1][jt] = __builtin_amdgcn_mfma_f32_16x16x32_bf16(jh, ih[1][ks], acc[1][jt], 0, 0, 0);
      }
    }

    // epilogue: key = nf[j] - 2*dot; j = j0 + jt*16 + quad*4 + r
    int jb = j0 + quad * 4;
    #pragma unroll
    for (int jt = 0; jt < 8; ++jt) {
      float4 nv = *(const float4*)(nfb + jb + jt * 16);
      float nfa[4] = {nv.x, nv.y, nv.z, nv.w};
      #pragma unroll
      for (int it = 0; it < 2; ++it)
        #pragma unroll
        for (int r = 0; r < 4; ++r) {
          float key = fmaf(-2.0f, acc[it][jt][r], nfa[r]);
          int jv = jb + jt * 16 + r;
          ins4(key, jv, ck[it], cj[it]);
        }
    }
  }

  // merge across the 4 quads holding the same (it, col) rows
  #pragma unroll
  for (int it = 0; it < 2; ++it)
    #pragma unroll
    for (int m = 16; m < 64; m <<= 1) {
      float tk[4]; int tj[4];
      #pragma unroll
      for (int s = 0; s < 4; ++s) {
        tk[s] = __shfl_xor(ck[it][s], m, 64);
        tj[s] = __shfl_xor(cj[it][s], m, 64);
      }
      #pragma unroll
      for (int s = 0; s < 4; ++s) ins4(tk[s], tj[s], ck[it], cj[it]);
    }
  if (quad == 0) {
    #pragma unroll
    for (int it = 0; it < 2; ++it) {
      int row = b * N_DIM + i0 + w * 32 + it * 16 + col;
      int base = row * 16 + q * 4;
      #pragma unroll
      for (int s = 0; s < 4; ++s) cand[base + s] = cj[it][s];
    }
  }
}

// ---- kernel 2b: exact fp64 re-rank, lane-per-candidate (16 lanes/row) ----
// grid = (B*N)/16 = 2048 blocks. Disjoint j-quarters -> no duplicate cands.
__global__ __launch_bounds__(256) void refine_kernel(
    const float* __restrict__ xT, const double* __restrict__ nd,
    const int* __restrict__ cand, int* __restrict__ topk) {
  int t = threadIdx.x;
  int l = t & 15;
  int row = blockIdx.x * 16 + (t >> 4);   // [0, B*N)
  int b = row >> 11;
  int n = row & (N_DIM - 1);
  int j = cand[row * 16 + l];
  const float* xn = xT + ((size_t)b * N_DIM + n) * C_DIM;
  const float* xj = xT + ((size_t)b * N_DIM + j) * C_DIM;
  double dot = 0.0;
  #pragma unroll
  for (int c = 0; c < C_DIM; ++c)
    dot = fma((double)xn[c], (double)xj[c], dot);
  double key = fma(-2.0, dot, nd[b * N_DIM + j]);
  double k0 = key, k1 = DBL_MAX, k2 = DBL_MAX;
  int j0 = j, j1 = INT_MAX, j2 = INT_MAX;
  #pragma unroll
  for (int m = 1; m < 16; m <<= 1) {
    double t0 = __shfl_xor(k0, m, 64);
    double t1 = __shfl_xor(k1, m, 64);
    double t2 = __shfl_xor(k2, m, 64);
    int    u0 = __shfl_xor(j0, m, 64);
    int    u1 = __shfl_xor(j1, m, 64);
    int    u2 = __shfl_xor(j2, m, 64);
    insert3d(t0, u0, k0, k1, k2, j0, j1, j2);
    insert3d(t1, u1, k0, k1, k2, j0, j1, j2);
    insert3d(t2, u2, k0, k1, k2, j0, j1, j2);
  }
  if (l == 0) {
    int base = row * K_NN;
    topk[base + 0] = j0;
    topk[base + 1] = j1;
    topk[base + 2] = j2;
  }
}

// ---- kernel 3: gather neighbors (coalesced via xT) + conv ----
#define NT   64
#define NPAD 68
__global__ __launch_bounds__(256) void conv_kernel(
    const float* __restrict__ xT, const float* __restrict__ Wt,
    const float* __restrict__ bias, const int* __restrict__ topk,
    float* __restrict__ out) {
  __shared__ __align__(16) float nb[C_DIM * K_NN][NPAD];  // 52224 B
  int bid = blockIdx.x;
  int b  = bid >> 5;
  int n0 = (bid & 31) * NT;
  const float* xtb = xT + (size_t)b * N_DIM * C_DIM;
  const int* tk = topk + (b * N_DIM + n0) * K_NN;
  int t = threadIdx.x;

  #pragma unroll
  for (int p = 0; p < 12; ++p) {
    int u = p * 256 + t;            // 3072 tasks: 192 rows x 16 segs
    int seg = u & 15;
    int r   = u >> 4;               // r = k*64 + n
    int k = r >> 6, n = r & 63;
    int j = tk[n * K_NN + k];
    float4 v = *(const float4*)(xtb + (size_t)j * C_DIM + seg * 4);
    nb[(seg * 4 + 0) * 3 + k][n] = v.x;
    nb[(seg * 4 + 1) * 3 + k][n] = v.y;
    nb[(seg * 4 + 2) * 3 + k][n] = v.z;
    nb[(seg * 4 + 3) * 3 + k][n] = v.w;
  }
  __syncthreads();

  int ng = t & 15, og = t >> 4;
  float acc[4][4];
  #pragma unroll
  for (int oo = 0; oo < 4; ++oo) {
    float bv = bias[(og << 2) + oo];
    #pragma unroll
    for (int nn = 0; nn < 4; ++nn) acc[oo][nn] = bv;
  }
  const float* nbp = &nb[0][0] + (ng << 2);
  const float* wtp = Wt + (og << 2);
  #pragma unroll 4
  for (int ckk = 0; ckk < C_DIM * K_NN; ++ckk) {
    float4 nv = *(const float4*)(nbp + ckk * NPAD);
    float4 wv = *(const float4*)(wtp + ckk * O_DIM);
    float na[4] = {nv.x, nv.y, nv.z, nv.w};
    float wa[4] = {wv.x, wv.y, wv.z, wv.w};
    #pragma unroll
    for (int oo = 0; oo < 4; ++oo)
      #pragma unroll
      for (int nn = 0; nn < 4; ++nn)
        acc[oo][nn] = fmaf(wa[oo], na[nn], acc[oo][nn]);
  }
  #pragma unroll
  for (int oo = 0; oo < 4; ++oo) {
    int o = (og << 2) + oo;
    float4 v; v.x = acc[oo][0]; v.y = acc[oo][1]; v.z = acc[oo][2]; v.w = acc[oo][3];
    *(float4*)&out[(size_t)(b * O_DIM + o) * N_DIM + n0 + (ng << 2)] = v;
  }
}

extern "C" void kernel_launch(void* const* d_in, const int* in_sizes, int n_in,
                              void* d_out, int out_size, void* d_ws, size_t ws_size,
                              hipStream_t stream) {
  const float* x    = (const float*)d_in[0];   // [B][C][N]
  const float* W    = (const float*)d_in[1];   // [O][C][K]
  const float* bias = (const float*)d_in[2];   // [O]
  float* out = (float*)d_out;                  // [B][O][N]
  char* ws = (char*)d_ws;
  // ws layout (bytes):
  //   xT   fp32  [B][N][C]          @ 0         (8 MB)
  //   xTh  bf16  [B][N][C] swizzled @ 8388608   (4 MB)
  //   xTl  bf16  [B][N][C] swizzled @ 12582912  (4 MB)
  //   nd   fp64  [B*N]              @ 16777216  (256 KB)
  //   nf   fp32  [B*N]              @ 17039360  (128 KB)
  //   cand int   [B*N][16]          @ 17170432  (2 MB)
  //   topk int   [B*N][3]           @ 19267584  (384 KB)
  //   Wt   fp32  [C*K][O]           @ 19660800  (48 KB)
  float*          xT  = (float*)ws;
  unsigned short* xTh = (unsigned short*)(ws + 8388608);
  unsigned short* xTl = (unsigned short*)(ws + 12582912);
  double*         nd  = (double*)(ws + 16777216);
  float*          nfp = (float*)(ws + 17039360);
  int*            cd  = (int*)(ws + 17170432);
  int*            tk  = (int*)(ws + 19267584);
  float*          Wt  = (float*)(ws + 19660800);

  prep_kernel<<<B_DIM * (N_DIM / 64), 256, 0, stream>>>(x, xT, xTh, xTl, nd, nfp);
  wt_kernel<<<(O_DIM * C_DIM * K_NN) / 256, 256, 0, stream>>>(W, Wt);
  topk_kernel<<<B_DIM * 16 * 4, 256, 0, stream>>>(xTh, xTl, nfp, cd);
  refine_kernel<<<(B_DIM * N_DIM) / 16, 256, 0, stream>>>(xT, nd, cd, tk);
  conv_kernel<<<B_DIM * (N_DIM / NT), 256, 0, stream>>>(xT, Wt, bias, tk, out);
}

// Round 7
// 166.076 us; speedup vs baseline: 5.0316x; 1.0814x over previous
//
#include <hip/hip_runtime.h>
#include <cfloat>
#include <climits>

#define B_DIM 16
#define C_DIM 64
#define N_DIM 2048
#define O_DIM 64
#define K_NN  3

typedef __attribute__((ext_vector_type(8))) short bf16x8;
typedef __attribute__((ext_vector_type(4))) float floatx4;

__device__ __forceinline__ unsigned short f32_to_bf16_rne(float f) {
  unsigned int u = __float_as_uint(f);
  return (unsigned short)((u + 0x7fffu + ((u >> 16) & 1u)) >> 16);
}
__device__ __forceinline__ float bf16_to_f32(unsigned short h) {
  return __uint_as_float(((unsigned int)h) << 16);
}

// Lexicographic (d, j) insert into sorted-ascending top-3 (fp64, exact path).
__device__ __forceinline__ void insert3d(double d, int j,
    double &k0, double &k1, double &k2, int &j0, int &j1, int &j2) {
  bool c2 = (d < k2) || (d == k2 && j < j2);
  bool c1 = (d < k1) || (d == k1 && j < j1);
  bool c0 = (d < k0) || (d == k0 && j < j0);
  k2 = c1 ? k1 : (c2 ? d : k2);
  j2 = c1 ? j1 : (c2 ? j : j2);
  k1 = c0 ? k0 : (c1 ? d : k1);
  j1 = c0 ? j0 : (c1 ? j : j1);
  k0 = c0 ? d : k0;
  j0 = c0 ? j : j0;
}

// Branchless fp32 top-4 insert (membership only; exact re-rank later).
__device__ __forceinline__ void ins4(float key, int jv, float* k, int* j) {
  bool c3 = key < k[3], c2 = key < k[2], c1 = key < k[1], c0 = key < k[0];
  k[3] = c2 ? k[2] : (c3 ? key : k[3]);
  j[3] = c2 ? j[2] : (c3 ? jv  : j[3]);
  k[2] = c1 ? k[1] : (c2 ? key : k[2]);
  j[2] = c1 ? j[1] : (c2 ? jv  : j[2]);
  k[1] = c0 ? k[0] : (c1 ? key : k[1]);
  j[1] = c0 ? j[0] : (c1 ? jv  : j[1]);
  k[0] = c0 ? key : k[0];
  j[0] = c0 ? jv  : j[0];
}

// ---- kernel 1: x -> xT fp32 [B][N][C], bf16 hi/lo split (chunk-swizzled
// in memory: 16B chunk q of row n stored at q^(n&7)), fp64+fp32 norms ----
__global__ __launch_bounds__(256) void prep_kernel(
    const float* __restrict__ x, float* __restrict__ xT,
    unsigned short* __restrict__ xTh, unsigned short* __restrict__ xTl,
    double* __restrict__ nd, float* __restrict__ nf) {
  __shared__ __align__(16) float xs[C_DIM][68];
  int bid = blockIdx.x;              // B * N/64 = 512
  int b  = bid >> 5;
  int n0 = (bid & 31) * 64;
  int t = threadIdx.x;
  const float* xb = x + (size_t)b * C_DIM * N_DIM;
  #pragma unroll
  for (int r = 0; r < 4; ++r) {
    int idx = r * 256 + t;           // 1024 float4 tasks
    int c = idx >> 4;
    int qq = idx & 15;
    *(float4*)&xs[c][qq * 4] = *(const float4*)(xb + (size_t)c * N_DIM + n0 + qq * 4);
  }
  __syncthreads();
  int n = t >> 2, cg = t & 3;        // 64 n x 4 c-groups of 16
  float v[16];
  #pragma unroll
  for (int cc = 0; cc < 16; ++cc) v[cc] = xs[cg * 16 + cc][n];
  double ps = 0.0;
  #pragma unroll
  for (int cc = 0; cc < 16; ++cc) ps = fma((double)v[cc], (double)v[cc], ps);
  ps += __shfl_xor(ps, 1, 64);
  ps += __shfl_xor(ps, 2, 64);       // lanes t^1,t^2 share n
  size_t row = (size_t)b * N_DIM + n0 + n;
  #pragma unroll
  for (int qq = 0; qq < 4; ++qq) {
    float4 wv; wv.x = v[qq*4]; wv.y = v[qq*4+1]; wv.z = v[qq*4+2]; wv.w = v[qq*4+3];
    *(float4*)&xT[row * C_DIM + cg * 16 + qq * 4] = wv;
  }
  unsigned short hh[16], ll[16];
  #pragma unroll
  for (int cc = 0; cc < 16; ++cc) {
    hh[cc] = f32_to_bf16_rne(v[cc]);
    ll[cc] = f32_to_bf16_rne(v[cc] - bf16_to_f32(hh[cc]));
  }
  #pragma unroll
  for (int e = 0; e < 2; ++e) {
    int phys = (2 * cg + e) ^ (n & 7);
    unsigned int hp[4], lp[4];
    #pragma unroll
    for (int xk = 0; xk < 4; ++xk) {
      hp[xk] = (unsigned)hh[e*8 + 2*xk] | ((unsigned)hh[e*8 + 2*xk + 1] << 16);
      lp[xk] = (unsigned)ll[e*8 + 2*xk] | ((unsigned)ll[e*8 + 2*xk + 1] << 16);
    }
    ((uint4*)xTh)[row * 8 + phys] = *(uint4*)hp;
    ((uint4*)xTl)[row * 8 + phys] = *(uint4*)lp;
  }
  if (cg == 0) {
    nd[row] = ps;
    nf[row] = (float)ps;
  }
}

// ---- kernel 1b: transpose W [O][C*K] -> Wt [C*K][O] ----
__global__ __launch_bounds__(256) void wt_kernel(const float* __restrict__ W,
                                                 float* __restrict__ Wt) {
  int t = blockIdx.x * 256 + threadIdx.x;
  int o  = t / (C_DIM * K_NN);
  int ck = t - o * (C_DIM * K_NN);
  Wt[ck * O_DIM + o] = W[t];
}

// ---- kernel 2: split-bf16 MFMA distance sweep ----
// grid = B*32*4 = 2048 blocks (64-wide itile x j-quarter), 256 thr (4 waves).
// A-operand = J-tile (LDS, 32KB), B-operand = I-frags (registers).
// Wave w owns 16 i-rows (i0 + w*16 + col); 32 keys/lane/step.
// LDS 32KB -> up to 5 blocks/CU; grid 8 blocks/CU candidate pool.
__global__ __launch_bounds__(256, 4) void topk_kernel(
    const unsigned short* __restrict__ xTh, const unsigned short* __restrict__ xTl,
    const float* __restrict__ nf, int* __restrict__ cand) {
  __shared__ __align__(16) unsigned short Jh[128 * 64];  // 16 KB
  __shared__ __align__(16) unsigned short Jl[128 * 64];  // 16 KB
  int bid   = blockIdx.x;
  int q     = bid & 3;               // j-quarter
  int itile = (bid >> 2) & 31;       // 32 i-tiles of 64 rows
  int b     = bid >> 7;
  int i0    = itile * 64;
  int jq0   = q * 512;
  int t = threadIdx.x;
  int w = t >> 6, lane = t & 63, quad = lane >> 4, col = lane & 15;
  int csw = col & 7;
  const unsigned short* xh = xTh + (size_t)b * N_DIM * 64;
  const unsigned short* xl = xTl + (size_t)b * N_DIM * 64;
  const float* nfb = nf + b * N_DIM;

  // I-frags (B operand) once from global. row&7 == col&7 == csw.
  bf16x8 ih[2], il[2];               // [ks]
  #pragma unroll
  for (int ks = 0; ks < 2; ++ks) {
    size_t row = i0 + w * 16 + col;
    int phys = (ks * 4 + quad) ^ csw;
    ih[ks] = *(const bf16x8*)(xh + row * 64 + phys * 8);
    il[ks] = *(const bf16x8*)(xl + row * 64 + phys * 8);
  }

  float ck[4]; int cj[4];
  #pragma unroll
  for (int s = 0; s < 4; ++s) { ck[s] = FLT_MAX; cj[s] = 0; }

  int a0 = col * 64 + ((quad ^ csw) * 8);        // ks=0 frag offset (shorts)
  int a1 = col * 64 + (((4 + quad) ^ csw) * 8);  // ks=1

  for (int js = 0; js < 4; ++js) {
    int j0 = jq0 + js * 128;
    __syncthreads();                 // prior frag reads done before overwrite
    {
      // stage 32 j-rows (Jh+Jl) per wave: pure 16B copies, layout verbatim
      const unsigned short* sh = xh + (size_t)(j0 + w * 32) * 64;
      const unsigned short* sl = xl + (size_t)(j0 + w * 32) * 64;
      unsigned short* dh = &Jh[w * 32 * 64];
      unsigned short* dl = &Jl[w * 32 * 64];
      int off = lane * 8;
      #pragma unroll
      for (int k2 = 0; k2 < 4; ++k2) {
        *(uint4*)(dh + k2 * 512 + off) = *(const uint4*)(sh + k2 * 512 + off);
        *(uint4*)(dl + k2 * 512 + off) = *(const uint4*)(sl + k2 * 512 + off);
      }
    }
    __syncthreads();

    floatx4 acc[8];
    #pragma unroll
    for (int jt = 0; jt < 8; ++jt) acc[jt] = (floatx4){0.f, 0.f, 0.f, 0.f};

    #pragma unroll
    for (int ks = 0; ks < 2; ++ks) {
      int ab = ks ? a1 : a0;
      #pragma unroll
      for (int jt = 0; jt < 8; ++jt) {
        bf16x8 jh = *(const bf16x8*)&Jh[jt * 1024 + ab];
        bf16x8 jl = *(const bf16x8*)&Jl[jt * 1024 + ab];
        acc[jt] = __builtin_amdgcn_mfma_f32_16x16x32_bf16(jl, ih[ks], acc[jt], 0, 0, 0);
        acc[jt] = __builtin_amdgcn_mfma_f32_16x16x32_bf16(jh, il[ks], acc[jt], 0, 0, 0);
        acc[jt] = __builtin_amdgcn_mfma_f32_16x16x32_bf16(jh, ih[ks], acc[jt], 0, 0, 0);
      }
    }

    // epilogue: key = nf[j] - 2*dot; j = j0 + jt*16 + quad*4 + r
    int jb = j0 + quad * 4;
    #pragma unroll
    for (int jt = 0; jt < 8; ++jt) {
      float4 nv = *(const float4*)(nfb + jb + jt * 16);
      float nfa[4] = {nv.x, nv.y, nv.z, nv.w};
      #pragma unroll
      for (int r = 0; r < 4; ++r) {
        float key = fmaf(-2.0f, acc[jt][r], nfa[r]);
        int jv = jb + jt * 16 + r;
        ins4(key, jv, ck, cj);
      }
    }
  }

  // merge across the 4 quads holding the same col (= same i-row)
  #pragma unroll
  for (int m = 16; m < 64; m <<= 1) {
    float tk[4]; int tj[4];
    #pragma unroll
    for (int s = 0; s < 4; ++s) {
      tk[s] = __shfl_xor(ck[s], m, 64);
      tj[s] = __shfl_xor(cj[s], m, 64);
    }
    #pragma unroll
    for (int s = 0; s < 4; ++s) ins4(tk[s], tj[s], ck, cj);
  }
  if (quad == 0) {
    int row = b * N_DIM + i0 + w * 16 + col;
    int base = row * 16 + q * 4;
    #pragma unroll
    for (int s = 0; s < 4; ++s) cand[base + s] = cj[s];
  }
}

// ---- kernel 2b: exact fp64 re-rank, coalesced cooperative loads ----
// Wave per row; lane = cand(0..15)*4 + seg(0..3); each lane reads 16
// channels (4 x float4) of its candidate row -> 16-line gathers instead
// of 64-line scalar gathers (the r6 straggler). grid = (B*N)/4 = 8192.
__global__ __launch_bounds__(256) void refine_kernel(
    const float* __restrict__ xT, const double* __restrict__ nd,
    const int* __restrict__ cand, int* __restrict__ topk) {
  int t = threadIdx.x;
  int lane = t & 63;
  int row = blockIdx.x * 4 + (t >> 6);   // [0, B*N)
  int b = row >> 11;
  int n = row & (N_DIM - 1);
  int cid = lane >> 2;
  int seg = lane & 3;
  int j = cand[row * 16 + cid];
  const float* xn = xT + (((size_t)b * N_DIM + n) * C_DIM) + seg * 16;
  const float* xj = xT + (((size_t)b * N_DIM + j) * C_DIM) + seg * 16;
  double dot = 0.0;
  #pragma unroll
  for (int qq = 0; qq < 4; ++qq) {
    float4 a  = *(const float4*)(xn + qq * 4);
    float4 bb = *(const float4*)(xj + qq * 4);
    dot = fma((double)a.x, (double)bb.x, dot);
    dot = fma((double)a.y, (double)bb.y, dot);
    dot = fma((double)a.z, (double)bb.z, dot);
    dot = fma((double)a.w, (double)bb.w, dot);
  }
  dot += __shfl_xor(dot, 1, 64);     // reduce over seg
  dot += __shfl_xor(dot, 2, 64);
  double key = fma(-2.0, dot, nd[b * N_DIM + j]);
  double k0 = key, k1 = DBL_MAX, k2 = DBL_MAX;
  int j0 = j, j1 = INT_MAX, j2 = INT_MAX;
  #pragma unroll
  for (int m = 4; m < 64; m <<= 1) {  // merge across the 16 cand groups
    double t0 = __shfl_xor(k0, m, 64);
    double t1 = __shfl_xor(k1, m, 64);
    double t2 = __shfl_xor(k2, m, 64);
    int    u0 = __shfl_xor(j0, m, 64);
    int    u1 = __shfl_xor(j1, m, 64);
    int    u2 = __shfl_xor(j2, m, 64);
    insert3d(t0, u0, k0, k1, k2, j0, j1, j2);
    insert3d(t1, u1, k0, k1, k2, j0, j1, j2);
    insert3d(t2, u2, k0, k1, k2, j0, j1, j2);
  }
  if (lane == 0) {
    int base = row * K_NN;
    topk[base + 0] = j0;
    topk[base + 1] = j1;
    topk[base + 2] = j2;
  }
}

// ---- kernel 3: gather neighbors (coalesced via xT) + conv ----
#define NT   64
#define NPAD 68
__global__ __launch_bounds__(256) void conv_kernel(
    const float* __restrict__ xT, const float* __restrict__ Wt,
    const float* __restrict__ bias, const int* __restrict__ topk,
    float* __restrict__ out) {
  __shared__ __align__(16) float nb[C_DIM * K_NN][NPAD];  // 52224 B
  int bid = blockIdx.x;
  int b  = bid >> 5;
  int n0 = (bid & 31) * NT;
  const float* xtb = xT + (size_t)b * N_DIM * C_DIM;
  const int* tk = topk + (b * N_DIM + n0) * K_NN;
  int t = threadIdx.x;

  #pragma unroll
  for (int p = 0; p < 12; ++p) {
    int u = p * 256 + t;            // 3072 tasks: 192 rows x 16 segs
    int seg = u & 15;
    int r   = u >> 4;               // r = k*64 + n
    int k = r >> 6, n = r & 63;
    int j = tk[n * K_NN + k];
    float4 v = *(const float4*)(xtb + (size_t)j * C_DIM + seg * 4);
    nb[(seg * 4 + 0) * 3 + k][n] = v.x;
    nb[(seg * 4 + 1) * 3 + k][n] = v.y;
    nb[(seg * 4 + 2) * 3 + k][n] = v.z;
    nb[(seg * 4 + 3) * 3 + k][n] = v.w;
  }
  __syncthreads();

  int ng = t & 15, og = t >> 4;
  float acc[4][4];
  #pragma unroll
  for (int oo = 0; oo < 4; ++oo) {
    float bv = bias[(og << 2) + oo];
    #pragma unroll
    for (int nn = 0; nn < 4; ++nn) acc[oo][nn] = bv;
  }
  const float* nbp = &nb[0][0] + (ng << 2);
  const float* wtp = Wt + (og << 2);
  #pragma unroll 4
  for (int ckk = 0; ckk < C_DIM * K_NN; ++ckk) {
    float4 nv = *(const float4*)(nbp + ckk * NPAD);
    float4 wv = *(const float4*)(wtp + ckk * O_DIM);
    float na[4] = {nv.x, nv.y, nv.z, nv.w};
    float wa[4] = {wv.x, wv.y, wv.z, wv.w};
    #pragma unroll
    for (int oo = 0; oo < 4; ++oo)
      #pragma unroll
      for (int nn = 0; nn < 4; ++nn)
        acc[oo][nn] = fmaf(wa[oo], na[nn], acc[oo][nn]);
  }
  #pragma unroll
  for (int oo = 0; oo < 4; ++oo) {
    int o = (og << 2) + oo;
    float4 v; v.x = acc[oo][0]; v.y = acc[oo][1]; v.z = acc[oo][2]; v.w = acc[oo][3];
    *(float4*)&out[(size_t)(b * O_DIM + o) * N_DIM + n0 + (ng << 2)] = v;
  }
}

extern "C" void kernel_launch(void* const* d_in, const int* in_sizes, int n_in,
                              void* d_out, int out_size, void* d_ws, size_t ws_size,
                              hipStream_t stream) {
  const float* x    = (const float*)d_in[0];   // [B][C][N]
  const float* W    = (const float*)d_in[1];   // [O][C][K]
  const float* bias = (const float*)d_in[2];   // [O]
  float* out = (float*)d_out;                  // [B][O][N]
  char* ws = (char*)d_ws;
  // ws layout (bytes):
  //   xT   fp32  [B][N][C]          @ 0         (8 MB)
  //   xTh  bf16  [B][N][C] swizzled @ 8388608   (4 MB)
  //   xTl  bf16  [B][N][C] swizzled @ 12582912  (4 MB)
  //   nd   fp64  [B*N]              @ 16777216  (256 KB)
  //   nf   fp32  [B*N]              @ 17039360  (128 KB)
  //   cand int   [B*N][16]          @ 17170432  (2 MB)
  //   topk int   [B*N][3]           @ 19267584  (384 KB)
  //   Wt   fp32  [C*K][O]           @ 19660800  (48 KB)
  float*          xT  = (float*)ws;
  unsigned short* xTh = (unsigned short*)(ws + 8388608);
  unsigned short* xTl = (unsigned short*)(ws + 12582912);
  double*         nd  = (double*)(ws + 16777216);
  float*          nfp = (float*)(ws + 17039360);
  int*            cd  = (int*)(ws + 17170432);
  int*            tk  = (int*)(ws + 19267584);
  float*          Wt  = (float*)(ws + 19660800);

  prep_kernel<<<B_DIM * (N_DIM / 64), 256, 0, stream>>>(x, xT, xTh, xTl, nd, nfp);
  wt_kernel<<<(O_DIM * C_DIM * K_NN) / 256, 256, 0, stream>>>(W, Wt);
  topk_kernel<<<B_DIM * 32 * 4, 256, 0, stream>>>(xTh, xTl, nfp, cd);
  refine_kernel<<<(B_DIM * N_DIM) / 4, 256, 0, stream>>>(xT, nd, cd, tk);
  conv_kernel<<<B_DIM * (N_DIM / NT), 256, 0, stream>>>(xT, Wt, bias, tk, out);
}